// Round 7
// baseline (9179.293 us; speedup 1.0000x reference)
//
#include <hip/hip_runtime.h>
#include <math.h>

// ---------------- problem constants ----------------
#define NBLK 192
#define NTHR 256
#define NL0B 64       // blocks 0..63 -> layer0 (16 h-cols each); 64..191 -> layer1 (8 h-cols)
#define BATCH 64
#define TT 512
#define INF 256
#define OUTF 256

typedef _Float16 f16;
typedef __attribute__((ext_vector_type(4))) _Float16 f16x4;
typedef __attribute__((ext_vector_type(8))) _Float16 f16x8;
typedef __attribute__((ext_vector_type(4))) float f32x4;
typedef __attribute__((ext_vector_type(4))) int i32x4;

// Workspace: S0[2], S1[2] rings ([64][1024] f16 = 128 KiB each), then flags.
// Producers write S with sc0+sc1 (write-through, L3-visible, no dirty L2).
// Consumers read S with PLAIN CACHED loads + one agent-acquire fence (L2
// invalidate, no writeback) per block per round -> per-XCD L2 dedup of the
// h-broadcast (each XCD fetches each line once instead of per-block).
#define SBUF_ELEMS 65536
#define S1_BASE (2 * SBUF_ELEMS)
#define FLAGS_OFF_BYTES ((size_t)4 * SBUF_ELEMS * 2)   // 512 KiB
#define WS_BYTES (FLAGS_OFF_BYTES + 256 * 4)

// LDS: 128 KiB weights + 2 KiB h-stage.
#define STAGE_OFF 131072
#define LDS_BYTES (131072 + 2048)

#define BARRIER_DEADLINE_TICKS 4000000ull   // 40 ms @100MHz; sticky bail

__device__ __forceinline__ float sig_(float v) { return 1.0f / (1.0f + __expf(-v)); }

// acquire-only fence: waits + invalidates L1/L2 tags (no writeback walk).
#define ACQ_FENCE() __builtin_amdgcn_fence(__ATOMIC_ACQUIRE, "agent")

#define GLOADX4(dst, p) \
  asm volatile("global_load_dwordx4 %0, %1, off" : "=v"(dst) : "v"(p))
#define GLOADX4_C(dst, p) \
  asm volatile("global_load_dwordx4 %0, %1, off" : "=v"(dst) : "v"(p))
#define GSTOREX4(p, v_) \
  asm volatile("global_store_dwordx4 %0, %1, off sc0 sc1" :: "v"(p), "v"(v_) : "memory")
#define VWAIT(N) do { \
  asm volatile("s_waitcnt vmcnt(" #N ")" ::: "memory"); \
  __builtin_amdgcn_sched_barrier(0); } while (0)

#define MFMA(a, b, c) __builtin_amdgcn_mfma_f32_16x16x32_f16(a, b, c, 0, 0, 0)

__device__ __forceinline__ f16x8 cvt8(float4 u, float4 v) {
  f16x8 r;
  r[0]=(f16)u.x; r[1]=(f16)u.y; r[2]=(f16)u.z; r[3]=(f16)u.w;
  r[4]=(f16)v.x; r[5]=(f16)v.y; r[6]=(f16)v.z; r[7]=(f16)v.w;
  return r;
}

// Grid barrier (proven order): all waves drain own stores -> __syncthreads ->
// tid0 publishes flags[b]=tgt (sc1) -> wave 0 polls all 192 flags (one
// dwordx4 per lane, tid<48, uncached). Deadline-bail sticky.
__device__ __forceinline__ void grid_barrier(int* flags, int tgt, bool& bail) {
  asm volatile("s_waitcnt vmcnt(0)" ::: "memory");
  __syncthreads();
  if (threadIdx.x == 0) {
    int* fp = flags + blockIdx.x;
    asm volatile("global_store_dword %0, %1, off sc0 sc1" :: "v"(fp), "v"(tgt) : "memory");
  }
  if (threadIdx.x < 64 && !bail) {
    const int* pp = flags + (threadIdx.x << 2);
    const unsigned long long t0 = __builtin_amdgcn_s_memrealtime();
    for (;;) {
      int ok = 1;
      if (threadIdx.x < 48) {
        i32x4 f4;
        asm volatile("global_load_dwordx4 %0, %1, off sc0 sc1\n\ts_waitcnt vmcnt(0)"
                     : "=v"(f4) : "v"(pp) : "memory");
        ok = (f4[0] >= tgt) & (f4[1] >= tgt) & (f4[2] >= tgt) & (f4[3] >= tgt);
      }
      if (__all(ok)) break;
      if (__builtin_amdgcn_s_memrealtime() - t0 > BARRIER_DEADLINE_TICKS) { bail = true; break; }
      __builtin_amdgcn_s_sleep(1);
    }
  }
  __syncthreads();
}

__global__ __launch_bounds__(NTHR, 1) void lstm_fused(
    const float* __restrict__ x,
    const float* __restrict__ w_ih_0, const float* __restrict__ w_hh_0,
    const float* __restrict__ b_ih_0, const float* __restrict__ b_hh_0,
    const float* __restrict__ w_ih_1, const float* __restrict__ w_hh_1,
    const float* __restrict__ b_ih_1, const float* __restrict__ b_hh_1,
    const float* __restrict__ w_fc, const float* __restrict__ b_fc,
    float* __restrict__ out, void* __restrict__ ws)
{
  extern __shared__ char smem[];
  f16* wl = (f16*)smem;
  f16* stage = (f16*)(smem + STAGE_OFF);
  f16* ws16 = (f16*)ws;
  int* flags = (int*)((char*)ws + FLAGS_OFF_BYTES);

  const int b = blockIdx.x;
  const int tid = threadIdx.x;
  const int wave = tid >> 6, lane = tid & 63;
  const int col = lane & 15, krow = lane >> 4;
  const bool isL1 = (b >= NL0B);
  bool bail = false;

  // ---- zero the S rings (512 KiB) via sc1 stores (drained at first barrier) ----
  {
    const int gt = b * NTHR + tid;
    if (gt < 32768) {
      i32x4 z = (i32x4){0, 0, 0, 0};
      char* p = (char*)ws + (size_t)gt * 16;
      GSTOREX4(p, z);
    }
  }

  if (!isL1) {
    // ================= LAYER 0: 64 blocks x 16 h-cols =================
    const int hc0 = b * 16;
    // LDS weights: s0-part (K=1024), layout [(kc*4+krow)][64 cols][8]
    {
      const int c2 = tid >> 2, kpart = tid & 3;        // c2: 0..63, kpart: 0..3
      const int n = c2 >> 4, cc = c2 & 15;
      const int grow = n * 1024 + hc0 + cc;
      const float* src = w_hh_0 + (size_t)grow * 1024;
      for (int k = kpart * 256; k < kpart * 256 + 256; k += 4) {
        float4 v = *(const float4*)(src + k);
        f16x4 hv; hv[0]=(f16)v.x; hv[1]=(f16)v.y; hv[2]=(f16)v.z; hv[3]=(f16)v.w;
        *(f16x4*)&wl[((size_t)(k >> 3) * 64 + c2) * 8 + (k & 7)] = hv;
      }
    }
    // x-weights in VGPRs: wx[n*8+kc], frag for (ntile n, kchunk kc of K=256)
    f16x8 wx[32];
#pragma unroll
    for (int n = 0; n < 4; ++n)
#pragma unroll
      for (int kc = 0; kc < 8; ++kc) {
        const float* p = w_ih_0 + (size_t)(n * 1024 + hc0 + col) * 256 + kc * 32 + krow * 8;
        wx[n * 8 + kc] = cvt8(*(const float4*)p, *(const float4*)(p + 4));
      }
    // biases (per-lane, all 16 cols active)
    const int gi = hc0 + col;
    const float bi  = b_ih_0[gi]        + b_hh_0[gi];
    const float bf_ = b_ih_0[1024 + gi] + b_hh_0[1024 + gi];
    const float bg  = b_ih_0[2048 + gi] + b_hh_0[2048 + gi];
    const float bo  = b_ih_0[3072 + gi] + b_hh_0[3072 + gi];
    float creg[4] = {0.f, 0.f, 0.f, 0.f};

    // prologue x-GEMM for t=0 (plain cached loads; nothing else in flight)
    f32x4 accX[4] = {{0,0,0,0},{0,0,0,0},{0,0,0,0},{0,0,0,0}};
    {
      const float* xb0 = x + (size_t)(16 * wave + col) * TT * INF + krow * 8;
#pragma unroll
      for (int kc = 0; kc < 8; ++kc) {
        f16x8 ax = cvt8(*(const float4*)(xb0 + kc * 32), *(const float4*)(xb0 + kc * 32 + 4));
#pragma unroll
        for (int n = 0; n < 4; ++n) accX[n] = MFMA(ax, wx[n * 8 + kc], accX[n]);
      }
    }
    grid_barrier(flags, 1, bail);

    const f16* WbL0 = wl + krow * 512 + col * 8;
    for (int r = 0; r <= TT; ++r) {
      if (r < TT) {
        // invalidate L1/L2 so this round's cached S-reads see the fresh ring
        ACQ_FENCE();
        f32x4 acc0 = accX[0], acc1 = accX[1], acc2 = accX[2], acc3 = accX[3];
        const f16* s0in = ws16 + (size_t)((r + 1) & 1) * SBUF_ELEMS;
        f16*       s0out = ws16 + (size_t)(r & 1) * SBUF_ELEMS;
        i32x4 xv[16], av[32];
        const bool dox = (r + 1) < TT;
        const float* xb = x + (size_t)(16 * wave + col) * TT * INF
                            + (size_t)(dox ? r + 1 : r) * INF + krow * 8;
        // 16 plain x loads (t=r+1): xv[2kc],xv[2kc+1] cover k = kc*32+krow*8 .. +8
#pragma unroll
        for (int i = 0; i < 16; ++i) {
          const float* p = xb + (i >> 1) * 32 + (i & 1) * 4;
          GLOADX4_C(xv[i], p);
        }
        const f16* Ab = s0in + (size_t)(16 * wave + col) * 1024 + krow * 8;
#pragma unroll
        for (int i = 0; i < 16; ++i) { const f16* p = Ab + i * 32; GLOADX4(av[i], p); }
        // consume x -> next round's accX (oldest-first: 32 outstanding here)
        accX[0] = (f32x4){0,0,0,0}; accX[1] = (f32x4){0,0,0,0};
        accX[2] = (f32x4){0,0,0,0}; accX[3] = (f32x4){0,0,0,0};
#define XSTEP(KC, NWAIT) do { VWAIT(NWAIT); \
    f16x8 ax_ = cvt8(__builtin_bit_cast(float4, xv[2*(KC)]), \
                     __builtin_bit_cast(float4, xv[2*(KC)+1])); \
    _Pragma("unroll") for (int n_ = 0; n_ < 4; ++n_) \
      accX[n_] = MFMA(ax_, wx[n_ * 8 + (KC)], accX[n_]); } while (0)
        XSTEP(0, 30); XSTEP(1, 28); XSTEP(2, 26); XSTEP(3, 24);
        XSTEP(4, 22); XSTEP(5, 20); XSTEP(6, 18); XSTEP(7, 16);
#undef XSTEP
        // second half of s0 loads (av[16..31]); outstanding back to 32
#pragma unroll
        for (int i = 16; i < 32; ++i) { const f16* p = Ab + i * 32; GLOADX4(av[i], p); }
        // consume s0 (32 kchunks x 4 ntiles)
#define CONS8L0(I0) do { _Pragma("unroll") for (int q_ = 0; q_ < 8; ++q_) { \
    f16x8 a_ = __builtin_bit_cast(f16x8, av[(I0) + q_]); \
    const f16* wp_ = WbL0 + ((I0) + q_) * 2048; \
    f16x8 w0_ = *(const f16x8*)(wp_); \
    f16x8 w1_ = *(const f16x8*)(wp_ + 128); \
    f16x8 w2_ = *(const f16x8*)(wp_ + 256); \
    f16x8 w3_ = *(const f16x8*)(wp_ + 384); \
    acc0 = MFMA(a_, w0_, acc0); acc1 = MFMA(a_, w1_, acc1); \
    acc2 = MFMA(a_, w2_, acc2); acc3 = MFMA(a_, w3_, acc3); } } while (0)
        VWAIT(24); CONS8L0(0);
        VWAIT(16); CONS8L0(8);
        VWAIT(8);  CONS8L0(16);
        VWAIT(0);  CONS8L0(24);
#undef CONS8L0
        // epilogue: direct 4-gate (no shfl), stage h in LDS, coalesced store
#pragma unroll
        for (int j = 0; j < 4; ++j) {
          float iv = acc0[j] + bi, fv = acc1[j] + bf_;
          float gv = acc2[j] + bg, ov = acc3[j] + bo;
          float cn = sig_(fv) * creg[j] + sig_(iv) * tanhf(gv);
          float hn = sig_(ov) * tanhf(cn);
          creg[j] = cn;
          stage[(16 * wave + krow * 4 + j) * 16 + col] = (f16)hn;
        }
        __syncthreads();
        if (tid < 64) {
          i32x4 v0 = *(const i32x4*)&stage[tid * 16];
          i32x4 v1 = *(const i32x4*)&stage[tid * 16 + 8];
          f16* p = s0out + (size_t)tid * 1024 + hc0;
          GSTOREX4(p, v0);
          f16* p2 = p + 8;
          GSTOREX4(p2, v1);
        }
      } else {
        __syncthreads();
      }
      grid_barrier(flags, r + 2, bail);
    }
  } else {
    // ================= LAYER 1: 128 blocks x 8 h-cols =================
    const int bb = b - NL0B;
    const int hc0 = bb * 8;
    // LDS weights: K=2048 (s0|s1), layout [(kc*4+krow)][32 cols][8]
    {
      const int c = tid >> 3, kpart = tid & 7;         // c: 0..31, kpart: 0..7
      const int grp = c >> 3, sub = c & 7;
      const int grow = grp * 1024 + hc0 + sub;
      const float* srcA = w_ih_1 + (size_t)grow * 1024;
      const float* srcB = w_hh_1 + (size_t)grow * 1024;
      for (int k = kpart * 256; k < kpart * 256 + 256; k += 4) {
        const float* s = (k < 1024) ? (srcA + k) : (srcB + (k - 1024));
        float4 v = *(const float4*)s;
        f16x4 hv; hv[0]=(f16)v.x; hv[1]=(f16)v.y; hv[2]=(f16)v.z; hv[3]=(f16)v.w;
        *(f16x4*)&wl[((size_t)(k >> 3) * 32 + c) * 8 + (k & 7)] = hv;
      }
    }
    const int gi = hc0 + (col & 7);
    const float bi  = b_ih_1[gi]        + b_hh_1[gi];
    const float bf_ = b_ih_1[1024 + gi] + b_hh_1[1024 + gi];
    const float bg  = b_ih_1[2048 + gi] + b_hh_1[2048 + gi];
    const float bo  = b_ih_1[3072 + gi] + b_hh_1[3072 + gi];
    float creg[4] = {0.f, 0.f, 0.f, 0.f};

    grid_barrier(flags, 1, bail);

    const f16* Wb = wl + krow * 256 + col * 8;
    for (int r = 0; r <= TT; ++r) {
      if (r >= 1) {
        ACQ_FENCE();
        const f16* s0in = ws16 + (size_t)((r + 1) & 1) * SBUF_ELEMS;
        const f16* s1in = ws16 + S1_BASE + (size_t)(r & 1) * SBUF_ELEMS;
        f16*       s1out = ws16 + S1_BASE + (size_t)((r + 1) & 1) * SBUF_ELEMS;
        f32x4 acc0 = (f32x4){0,0,0,0}, acc1 = (f32x4){0,0,0,0};
        i32x4 av[64];
        const f16* Ab0 = s0in + (size_t)(16 * wave + col) * 1024 + krow * 8;
        const f16* Ab1 = s1in + (size_t)(16 * wave + col) * 1024 + krow * 8;
#pragma unroll
        for (int i = 0; i < 32; ++i) { const f16* p = Ab0 + i * 32; GLOADX4(av[i], p); }
#define CONS8(I0, KOFF) do { _Pragma("unroll") for (int q_ = 0; q_ < 8; ++q_) { \
    f16x8 a_ = __builtin_bit_cast(f16x8, av[(I0) + q_]); \
    const f16* wp_ = Wb + ((KOFF) + q_) * 1024; \
    f16x8 w0_ = *(const f16x8*)(wp_); \
    f16x8 w1_ = *(const f16x8*)(wp_ + 128); \
    acc0 = MFMA(a_, w0_, acc0); acc1 = MFMA(a_, w1_, acc1); } } while (0)
        VWAIT(24); CONS8(0, 0);
        VWAIT(16); CONS8(8, 8);
#pragma unroll
        for (int i = 0; i < 32; ++i) { const f16* p = Ab1 + i * 32; GLOADX4(av[32 + i], p); }
        VWAIT(40); CONS8(16, 16);
        VWAIT(32); CONS8(24, 24);
        VWAIT(24); CONS8(32, 32);
        VWAIT(16); CONS8(40, 40);
        VWAIT(8);  CONS8(48, 48);
        VWAIT(0);  CONS8(56, 56);
#undef CONS8
        // epilogue: i/f and g/o pairs via shfl; stage h; coalesced store
        f16 hv4[4];
#pragma unroll
        for (int j = 0; j < 4; ++j) {
          float iv = acc0[j], gv = acc1[j];
          float fv = __shfl_xor(iv, 8, 64);
          float ov = __shfl_xor(gv, 8, 64);
          iv += bi; fv += bf_; gv += bg; ov += bo;
          float cn = sig_(fv) * creg[j] + sig_(iv) * tanhf(gv);
          float hn = sig_(ov) * tanhf(cn);
          creg[j] = cn;
          hv4[j] = (f16)hn;
        }
        if (col < 8) {
#pragma unroll
          for (int j = 0; j < 4; ++j)
            stage[(16 * wave + krow * 4 + j) * 8 + col] = hv4[j];
        }
        __syncthreads();
        if (tid < 64) {
          i32x4 v0 = *(const i32x4*)&stage[tid * 8];
          f16* p = s1out + (size_t)tid * 1024 + hc0;
          GSTOREX4(p, v0);
        }
      } else {
        __syncthreads();
      }
      grid_barrier(flags, r + 2, bail);
    }
  }

  // ---- FC on last timestep: cols c = b, b+192 ----
  {
    ACQ_FENCE();   // s1[511] lines may be stale in this XCD's L2 from round 511
    float* red = (float*)smem;   // weights dead
    const f16* Afc = ws16 + S1_BASE + (size_t)1 * SBUF_ELEMS;   // s1[511] parity 1
    const int row = tid & 63, kq = tid >> 6;
    for (int c = b; c < OUTF; c += NBLK) {
      const f16* ph = Afc + (size_t)row * 1024 + kq * 256;
      const float* pw = w_fc + (size_t)c * 1024 + kq * 256;
      float acc = 0.f;
#pragma unroll 4
      for (int k = 0; k < 256; ++k)
        acc = fmaf((float)ph[k], pw[k], acc);
      __syncthreads();
      red[tid] = acc;
      __syncthreads();
      if (tid < 64) {
        float s = red[tid] + red[64 + tid] + red[128 + tid] + red[192 + tid] + b_fc[c];
        out[(size_t)tid * OUTF + c] = s;
      }
    }
  }
}

extern "C" void kernel_launch(void* const* d_in, const int* in_sizes, int n_in,
                              void* d_out, int out_size, void* d_ws, size_t ws_size,
                              hipStream_t stream) {
  const float* x      = (const float*)d_in[0];
  const float* w_ih_0 = (const float*)d_in[1];
  const float* w_hh_0 = (const float*)d_in[2];
  const float* b_ih_0 = (const float*)d_in[3];
  const float* b_hh_0 = (const float*)d_in[4];
  const float* w_ih_1 = (const float*)d_in[5];
  const float* w_hh_1 = (const float*)d_in[6];
  const float* b_ih_1 = (const float*)d_in[7];
  const float* b_hh_1 = (const float*)d_in[8];
  const float* w_fc   = (const float*)d_in[9];
  const float* b_fc   = (const float*)d_in[10];
  float* out = (float*)d_out;
  void* ws = d_ws;

  if (ws_size < WS_BYTES) return;   // clean failure signature, no VM fault

  hipMemsetAsync((char*)d_ws + FLAGS_OFF_BYTES, 0, 256 * 4, stream);
  hipFuncSetAttribute((const void*)lstm_fused,
                      hipFuncAttributeMaxDynamicSharedMemorySize, LDS_BYTES);

  void* args[] = {
    (void*)&x, (void*)&w_ih_0, (void*)&w_hh_0, (void*)&b_ih_0, (void*)&b_hh_0,
    (void*)&w_ih_1, (void*)&w_hh_1, (void*)&b_ih_1, (void*)&b_hh_1,
    (void*)&w_fc, (void*)&b_fc, (void*)&out, (void*)&ws
  };
  hipError_t err = hipLaunchCooperativeKernel((void*)lstm_fused, dim3(NBLK), dim3(NTHR),
                                              args, LDS_BYTES, stream);
  if (err != hipSuccess) {
    (void)hipGetLastError();
    lstm_fused<<<dim3(NBLK), dim3(NTHR), LDS_BYTES, stream>>>(
        x, w_ih_0, w_hh_0, b_ih_0, b_hh_0, w_ih_1, w_hh_1, b_ih_1, b_hh_1,
        w_fc, b_fc, out, ws);
  }
}

// Round 8
// 6483.569 us; speedup vs baseline: 1.4158x; 1.4158x over previous
//
#include <hip/hip_runtime.h>
#include <math.h>

// ---------------- problem constants ----------------
#define NBLK 192
#define NTHR 256
#define NL0B 64       // blocks 0..63 -> layer0 (16 h-cols each); 64..191 -> layer1 (8 h-cols)
#define BATCH 64
#define TT 512
#define INF 256
#define OUTF 256

typedef _Float16 f16;
typedef __attribute__((ext_vector_type(4))) _Float16 f16x4;
typedef __attribute__((ext_vector_type(8))) _Float16 f16x8;
typedef __attribute__((ext_vector_type(4))) float f32x4;
typedef __attribute__((ext_vector_type(4))) int i32x4;

// Workspace: S0[2], S1[2] rings ([64][1024] f16 = 128 KiB each), then flags.
// ALL S accesses are sc0+sc1 asm (L1/L2 bypass, L3-coherent) -> no fences.
#define SBUF_ELEMS 65536
#define S1_BASE (2 * SBUF_ELEMS)
#define FLAGS_OFF_BYTES ((size_t)4 * SBUF_ELEMS * 2)   // 512 KiB
#define WS_BYTES (FLAGS_OFF_BYTES + 256 * 4)

// LDS: 128 KiB weights + 2 KiB h-stage.
#define STAGE_OFF 131072
#define LDS_BYTES (131072 + 2048)

#define BARRIER_DEADLINE_TICKS 4000000ull   // 40 ms @100MHz; sticky bail

__device__ __forceinline__ float sig_(float v) { return 1.0f / (1.0f + __expf(-v)); }

#define GLOADX4(dst, p) \
  asm volatile("global_load_dwordx4 %0, %1, off sc0 sc1" : "=v"(dst) : "v"(p))
#define GLOADX4_C(dst, p) \
  asm volatile("global_load_dwordx4 %0, %1, off" : "=v"(dst) : "v"(p))
#define GSTOREX4(p, v_) \
  asm volatile("global_store_dwordx4 %0, %1, off sc0 sc1" :: "v"(p), "v"(v_) : "memory")
#define VWAIT(N) do { \
  asm volatile("s_waitcnt vmcnt(" #N ")" ::: "memory"); \
  __builtin_amdgcn_sched_barrier(0); } while (0)

#define MFMA(a, b, c) __builtin_amdgcn_mfma_f32_16x16x32_f16(a, b, c, 0, 0, 0)

__device__ __forceinline__ f16x8 cvt8(float4 u, float4 v) {
  f16x8 r;
  r[0]=(f16)u.x; r[1]=(f16)u.y; r[2]=(f16)u.z; r[3]=(f16)u.w;
  r[4]=(f16)v.x; r[5]=(f16)v.y; r[6]=(f16)v.z; r[7]=(f16)v.w;
  return r;
}

// Grid barrier (proven order): all waves drain own stores -> __syncthreads ->
// tid0 publishes flags[b]=tgt (sc1) -> wave 0 polls all 192 flags (one
// dwordx4 per lane, tid<48, uncached). Deadline-bail sticky.
__device__ __forceinline__ void grid_barrier(int* flags, int tgt, bool& bail) {
  asm volatile("s_waitcnt vmcnt(0)" ::: "memory");
  __syncthreads();
  if (threadIdx.x == 0) {
    int* fp = flags + blockIdx.x;
    asm volatile("global_store_dword %0, %1, off sc0 sc1" :: "v"(fp), "v"(tgt) : "memory");
  }
  if (threadIdx.x < 64 && !bail) {
    const int* pp = flags + (threadIdx.x << 2);
    const unsigned long long t0 = __builtin_amdgcn_s_memrealtime();
    for (;;) {
      int ok = 1;
      if (threadIdx.x < 48) {
        i32x4 f4;
        asm volatile("global_load_dwordx4 %0, %1, off sc0 sc1\n\ts_waitcnt vmcnt(0)"
                     : "=v"(f4) : "v"(pp) : "memory");
        ok = (f4[0] >= tgt) & (f4[1] >= tgt) & (f4[2] >= tgt) & (f4[3] >= tgt);
      }
      if (__all(ok)) break;
      if (__builtin_amdgcn_s_memrealtime() - t0 > BARRIER_DEADLINE_TICKS) { bail = true; break; }
      __builtin_amdgcn_s_sleep(1);
    }
  }
  __syncthreads();
}

__global__ __launch_bounds__(NTHR, 1) void lstm_fused(
    const float* __restrict__ x,
    const float* __restrict__ w_ih_0, const float* __restrict__ w_hh_0,
    const float* __restrict__ b_ih_0, const float* __restrict__ b_hh_0,
    const float* __restrict__ w_ih_1, const float* __restrict__ w_hh_1,
    const float* __restrict__ b_ih_1, const float* __restrict__ b_hh_1,
    const float* __restrict__ w_fc, const float* __restrict__ b_fc,
    float* __restrict__ out, void* __restrict__ ws)
{
  extern __shared__ char smem[];
  f16* wl = (f16*)smem;
  f16* stage = (f16*)(smem + STAGE_OFF);
  f16* ws16 = (f16*)ws;
  int* flags = (int*)((char*)ws + FLAGS_OFF_BYTES);

  const int b = blockIdx.x;
  const int tid = threadIdx.x;
  const int wave = tid >> 6, lane = tid & 63;
  const int col = lane & 15, krow = lane >> 4;
  const bool isL1 = (b >= NL0B);
  bool bail = false;

  // ---- zero the S rings (512 KiB) via sc1 stores (drained at first barrier) ----
  {
    const int gt = b * NTHR + tid;
    if (gt < 32768) {
      i32x4 z = (i32x4){0, 0, 0, 0};
      char* p = (char*)ws + (size_t)gt * 16;
      GSTOREX4(p, z);
    }
  }

  if (!isL1) {
    // ================= LAYER 0: 64 blocks x 16 h-cols =================
    const int hc0 = b * 16;
    // LDS weights: s0-part (K=1024), layout [(kc*4+krow)][64 cols][8]
    {
      const int c2 = tid >> 2, kpart = tid & 3;        // c2: 0..63, kpart: 0..3
      const int n = c2 >> 4, cc = c2 & 15;
      const int grow = n * 1024 + hc0 + cc;
      const float* src = w_hh_0 + (size_t)grow * 1024;
      for (int k = kpart * 256; k < kpart * 256 + 256; k += 4) {
        float4 v = *(const float4*)(src + k);
        f16x4 hv; hv[0]=(f16)v.x; hv[1]=(f16)v.y; hv[2]=(f16)v.z; hv[3]=(f16)v.w;
        *(f16x4*)&wl[((size_t)(k >> 3) * 64 + c2) * 8 + (k & 7)] = hv;
      }
    }
    // x-weights in VGPRs: wx[n*8+kc], frag for (ntile n, kchunk kc of K=256)
    f16x8 wx[32];
#pragma unroll
    for (int n = 0; n < 4; ++n)
#pragma unroll
      for (int kc = 0; kc < 8; ++kc) {
        const float* p = w_ih_0 + (size_t)(n * 1024 + hc0 + col) * 256 + kc * 32 + krow * 8;
        wx[n * 8 + kc] = cvt8(*(const float4*)p, *(const float4*)(p + 4));
      }
    // biases (per-lane, all 16 cols active)
    const int gi = hc0 + col;
    const float bi  = b_ih_0[gi]        + b_hh_0[gi];
    const float bf_ = b_ih_0[1024 + gi] + b_hh_0[1024 + gi];
    const float bg  = b_ih_0[2048 + gi] + b_hh_0[2048 + gi];
    const float bo  = b_ih_0[3072 + gi] + b_hh_0[3072 + gi];
    float creg[4] = {0.f, 0.f, 0.f, 0.f};

    // prologue x-GEMM for t=0 (plain cached loads; nothing else in flight)
    f32x4 accX0 = (f32x4){0,0,0,0}, accX1 = (f32x4){0,0,0,0};
    f32x4 accX2 = (f32x4){0,0,0,0}, accX3 = (f32x4){0,0,0,0};
    {
      const float* xb0 = x + (size_t)(16 * wave + col) * TT * INF + krow * 8;
#pragma unroll
      for (int kc = 0; kc < 8; ++kc) {
        f16x8 ax = cvt8(*(const float4*)(xb0 + kc * 32), *(const float4*)(xb0 + kc * 32 + 4));
        accX0 = MFMA(ax, wx[0 * 8 + kc], accX0);
        accX1 = MFMA(ax, wx[1 * 8 + kc], accX1);
        accX2 = MFMA(ax, wx[2 * 8 + kc], accX2);
        accX3 = MFMA(ax, wx[3 * 8 + kc], accX3);
      }
    }
    grid_barrier(flags, 1, bail);

    const f16* WbL0 = wl + krow * 512 + col * 8;
    for (int r = 0; r <= TT; ++r) {
      if (r < TT) {
        f32x4 acc0 = accX0, acc1 = accX1, acc2 = accX2, acc3 = accX3;
        const f16* s0in = ws16 + (size_t)((r + 1) & 1) * SBUF_ELEMS;
        f16*       s0out = ws16 + (size_t)(r & 1) * SBUF_ELEMS;
        const bool dox = (r + 1) < TT;
        const float* xb = x + (size_t)(16 * wave + col) * TT * INF
                            + (size_t)(dox ? r + 1 : r) * INF + krow * 8;
        accX0 = (f32x4){0,0,0,0}; accX1 = (f32x4){0,0,0,0};
        accX2 = (f32x4){0,0,0,0}; accX3 = (f32x4){0,0,0,0};
        // ---- x phase (t=r+1 -> accX): two serial 8-load groups, xv[8] ring ----
        i32x4 xv[8];
#define XGROUP(KC0) do { \
    _Pragma("unroll") for (int i = 0; i < 8; ++i) { \
      const float* p_ = xb + ((KC0) + (i >> 1)) * 32 + (i & 1) * 4; \
      GLOADX4_C(xv[i], p_); } \
    VWAIT(0); \
    _Pragma("unroll") for (int q = 0; q < 4; ++q) { \
      f16x8 ax_ = cvt8(__builtin_bit_cast(float4, xv[2 * q]), \
                       __builtin_bit_cast(float4, xv[2 * q + 1])); \
      accX0 = MFMA(ax_, wx[0 * 8 + (KC0) + q], accX0); \
      accX1 = MFMA(ax_, wx[1 * 8 + (KC0) + q], accX1); \
      accX2 = MFMA(ax_, wx[2 * 8 + (KC0) + q], accX2); \
      accX3 = MFMA(ax_, wx[3 * 8 + (KC0) + q], accX3); } \
  } while (0)
        XGROUP(0);
        XGROUP(4);
#undef XGROUP
        // ---- s0 phase: 32 chunks, 8-deep ring (av[8]), 4-chunk groups ----
        i32x4 av[8];
        const f16* Ab = s0in + (size_t)(16 * wave + col) * 1024 + krow * 8;
#pragma unroll
        for (int i = 0; i < 8; ++i) { const f16* p = Ab + i * 32; GLOADX4(av[i], p); }
#define L0GROUP(G, NWAIT, DOISSUE) do { \
    VWAIT(NWAIT); \
    _Pragma("unroll") for (int q = 0; q < 4; ++q) { \
      f16x8 a_ = __builtin_bit_cast(f16x8, av[((G) % 2) * 4 + q]); \
      const f16* wp_ = WbL0 + ((G) * 4 + q) * 2048; \
      f16x8 w0_ = *(const f16x8*)(wp_); \
      f16x8 w1_ = *(const f16x8*)(wp_ + 128); \
      f16x8 w2_ = *(const f16x8*)(wp_ + 256); \
      f16x8 w3_ = *(const f16x8*)(wp_ + 384); \
      acc0 = MFMA(a_, w0_, acc0); acc1 = MFMA(a_, w1_, acc1); \
      acc2 = MFMA(a_, w2_, acc2); acc3 = MFMA(a_, w3_, acc3); } \
    if (DOISSUE) { _Pragma("unroll") for (int q = 0; q < 4; ++q) { \
      const f16* p_ = Ab + (((G) + 2) * 4 + q) * 32; \
      GLOADX4(av[((G) % 2) * 4 + q], p_); } } \
  } while (0)
        L0GROUP(0, 4, 1); L0GROUP(1, 4, 1); L0GROUP(2, 4, 1);
        L0GROUP(3, 4, 1); L0GROUP(4, 4, 1); L0GROUP(5, 4, 1);
        L0GROUP(6, 4, 0); L0GROUP(7, 0, 0);
#undef L0GROUP
        // epilogue: direct 4-gate (no shfl), stage h in LDS, coalesced store
#pragma unroll
        for (int j = 0; j < 4; ++j) {
          float iv = acc0[j] + bi, fv = acc1[j] + bf_;
          float gv = acc2[j] + bg, ov = acc3[j] + bo;
          float cn = sig_(fv) * creg[j] + sig_(iv) * tanhf(gv);
          float hn = sig_(ov) * tanhf(cn);
          creg[j] = cn;
          stage[(16 * wave + krow * 4 + j) * 16 + col] = (f16)hn;
        }
        __syncthreads();
        if (tid < 64) {
          i32x4 v0 = *(const i32x4*)&stage[tid * 16];
          i32x4 v1 = *(const i32x4*)&stage[tid * 16 + 8];
          f16* p = s0out + (size_t)tid * 1024 + hc0;
          GSTOREX4(p, v0);
          f16* p2 = p + 8;
          GSTOREX4(p2, v1);
        }
      } else {
        __syncthreads();
      }
      grid_barrier(flags, r + 2, bail);
    }
  } else {
    // ================= LAYER 1: 128 blocks x 8 h-cols =================
    const int bb = b - NL0B;
    const int hc0 = bb * 8;
    // LDS weights: K=2048 (s0|s1), layout [(kc*4+krow)][32 cols][8]
    {
      const int c = tid >> 3, kpart = tid & 7;         // c: 0..31, kpart: 0..7
      const int grp = c >> 3, sub = c & 7;
      const int grow = grp * 1024 + hc0 + sub;
      const float* srcA = w_ih_1 + (size_t)grow * 1024;
      const float* srcB = w_hh_1 + (size_t)grow * 1024;
      for (int k = kpart * 256; k < kpart * 256 + 256; k += 4) {
        const float* s = (k < 1024) ? (srcA + k) : (srcB + (k - 1024));
        float4 v = *(const float4*)s;
        f16x4 hv; hv[0]=(f16)v.x; hv[1]=(f16)v.y; hv[2]=(f16)v.z; hv[3]=(f16)v.w;
        *(f16x4*)&wl[((size_t)(k >> 3) * 32 + c) * 8 + (k & 7)] = hv;
      }
    }
    const int gi = hc0 + (col & 7);
    const float bi  = b_ih_1[gi]        + b_hh_1[gi];
    const float bf_ = b_ih_1[1024 + gi] + b_hh_1[1024 + gi];
    const float bg  = b_ih_1[2048 + gi] + b_hh_1[2048 + gi];
    const float bo  = b_ih_1[3072 + gi] + b_hh_1[3072 + gi];
    float creg[4] = {0.f, 0.f, 0.f, 0.f};

    grid_barrier(flags, 1, bail);

    const f16* Wb = wl + krow * 256 + col * 8;
    for (int r = 0; r <= TT; ++r) {
      if (r >= 1) {
        const f16* s0in = ws16 + (size_t)((r + 1) & 1) * SBUF_ELEMS;
        const f16* s1in = ws16 + S1_BASE + (size_t)(r & 1) * SBUF_ELEMS;
        f16*       s1out = ws16 + S1_BASE + (size_t)((r + 1) & 1) * SBUF_ELEMS;
        f32x4 acc0 = (f32x4){0,0,0,0}, acc1 = (f32x4){0,0,0,0};
        const f16* Ab0 = s0in + (size_t)(16 * wave + col) * 1024 + krow * 8;
        const f16* Ab1 = s1in + (size_t)(16 * wave + col) * 1024 + krow * 8;
        // 64 chunks (0..31 from Ab0, 32..63 from Ab1); 24-deep ring av[24]
#define CHUNKP(c) ((c) < 32 ? (Ab0 + (c) * 32) : (Ab1 + ((c) - 32) * 32))
        i32x4 av[24];
#pragma unroll
        for (int i = 0; i < 24; ++i) { const f16* p = CHUNKP(i); GLOADX4(av[i], p); }
#define L1GROUP(G, NWAIT, DOISSUE) do { \
    VWAIT(NWAIT); \
    _Pragma("unroll") for (int q = 0; q < 8; ++q) { \
      f16x8 a_ = __builtin_bit_cast(f16x8, av[((G) % 3) * 8 + q]); \
      const f16* wp_ = Wb + ((G) * 8 + q) * 1024; \
      f16x8 w0_ = *(const f16x8*)(wp_); \
      f16x8 w1_ = *(const f16x8*)(wp_ + 128); \
      acc0 = MFMA(a_, w0_, acc0); acc1 = MFMA(a_, w1_, acc1); } \
    if (DOISSUE) { _Pragma("unroll") for (int q = 0; q < 8; ++q) { \
      const f16* p_ = CHUNKP(((G) + 3) * 8 + q); \
      GLOADX4(av[((G) % 3) * 8 + q], p_); } } \
  } while (0)
        L1GROUP(0, 16, 1); L1GROUP(1, 16, 1); L1GROUP(2, 16, 1);
        L1GROUP(3, 16, 1); L1GROUP(4, 16, 1);
        L1GROUP(5, 16, 0); L1GROUP(6, 8, 0); L1GROUP(7, 0, 0);
#undef L1GROUP
#undef CHUNKP
        // epilogue: i/f and g/o pairs via shfl; stage h; coalesced store
        f16 hv4[4];
#pragma unroll
        for (int j = 0; j < 4; ++j) {
          float iv = acc0[j], gv = acc1[j];
          float fv = __shfl_xor(iv, 8, 64);
          float ov = __shfl_xor(gv, 8, 64);
          iv += bi; fv += bf_; gv += bg; ov += bo;
          float cn = sig_(fv) * creg[j] + sig_(iv) * tanhf(gv);
          float hn = sig_(ov) * tanhf(cn);
          creg[j] = cn;
          hv4[j] = (f16)hn;
        }
        if (col < 8) {
#pragma unroll
          for (int j = 0; j < 4; ++j)
            stage[(16 * wave + krow * 4 + j) * 8 + col] = hv4[j];
        }
        __syncthreads();
        if (tid < 64) {
          i32x4 v0 = *(const i32x4*)&stage[tid * 8];
          f16* p = s1out + (size_t)tid * 1024 + hc0;
          GSTOREX4(p, v0);
        }
      } else {
        __syncthreads();
      }
      grid_barrier(flags, r + 2, bail);
    }
  }

  // ---- FC on last timestep: cols c = b, b+192 ----
  {
    float* red = (float*)smem;   // weights dead
    const f16* Afc = ws16 + S1_BASE + (size_t)1 * SBUF_ELEMS;   // s1[511] parity 1
    const int row = tid & 63, kq = tid >> 6;
    for (int c = b; c < OUTF; c += NBLK) {
      const f16* ph = Afc + (size_t)row * 1024 + kq * 256;
      const float* pw = w_fc + (size_t)c * 1024 + kq * 256;
      float acc = 0.f;
#pragma unroll 4
      for (int k = 0; k < 256; ++k)
        acc = fmaf((float)ph[k], pw[k], acc);
      __syncthreads();
      red[tid] = acc;
      __syncthreads();
      if (tid < 64) {
        float s = red[tid] + red[64 + tid] + red[128 + tid] + red[192 + tid] + b_fc[c];
        out[(size_t)tid * OUTF + c] = s;
      }
    }
  }
}

extern "C" void kernel_launch(void* const* d_in, const int* in_sizes, int n_in,
                              void* d_out, int out_size, void* d_ws, size_t ws_size,
                              hipStream_t stream) {
  const float* x      = (const float*)d_in[0];
  const float* w_ih_0 = (const float*)d_in[1];
  const float* w_hh_0 = (const float*)d_in[2];
  const float* b_ih_0 = (const float*)d_in[3];
  const float* b_hh_0 = (const float*)d_in[4];
  const float* w_ih_1 = (const float*)d_in[5];
  const float* w_hh_1 = (const float*)d_in[6];
  const float* b_ih_1 = (const float*)d_in[7];
  const float* b_hh_1 = (const float*)d_in[8];
  const float* w_fc   = (const float*)d_in[9];
  const float* b_fc   = (const float*)d_in[10];
  float* out = (float*)d_out;
  void* ws = d_ws;

  if (ws_size < WS_BYTES) return;   // clean failure signature, no VM fault

  hipMemsetAsync((char*)d_ws + FLAGS_OFF_BYTES, 0, 256 * 4, stream);
  hipFuncSetAttribute((const void*)lstm_fused,
                      hipFuncAttributeMaxDynamicSharedMemorySize, LDS_BYTES);

  void* args[] = {
    (void*)&x, (void*)&w_ih_0, (void*)&w_hh_0, (void*)&b_ih_0, (void*)&b_hh_0,
    (void*)&w_ih_1, (void*)&w_hh_1, (void*)&b_ih_1, (void*)&b_hh_1,
    (void*)&w_fc, (void*)&b_fc, (void*)&out, (void*)&ws
  };
  hipError_t err = hipLaunchCooperativeKernel((void*)lstm_fused, dim3(NBLK), dim3(NTHR),
                                              args, LDS_BYTES, stream);
  if (err != hipSuccess) {
    (void)hipGetLastError();
    lstm_fused<<<dim3(NBLK), dim3(NTHR), LDS_BYTES, stream>>>(
        x, w_ih_0, w_hh_0, b_ih_0, b_hh_0, w_ih_1, w_hh_1, b_ih_1, b_hh_1,
        w_fc, b_fc, out, ws);
  }
}

// Round 11
// 6442.406 us; speedup vs baseline: 1.4248x; 1.0064x over previous
//
#include <hip/hip_runtime.h>
#include <math.h>

// ---------------- problem constants ----------------
#define NBLK 192
#define NTHR 512      // 8 waves: waves 0-3 = K-half 0, waves 4-7 = K-half 1
#define NL0B 64       // blocks 0..63 -> layer0 (16 h-cols); 64..191 -> layer1 (8 h-cols)
#define BATCH 64
#define TT 512
#define INF 256
#define OUTF 256

typedef _Float16 f16;
typedef __attribute__((ext_vector_type(4))) _Float16 f16x4;
typedef __attribute__((ext_vector_type(8))) _Float16 f16x8;
typedef __attribute__((ext_vector_type(4))) float f32x4;
typedef __attribute__((ext_vector_type(4))) int i32x4;

// Workspace: S0[2], S1[2] rings ([64][1024] f16 = 128 KiB each), then flags.
// ALL S accesses are sc0+sc1 asm (L1/L2 bypass, L3-coherent) -> no fences.
#define SBUF_ELEMS 65536
#define S1_BASE (2 * SBUF_ELEMS)
#define FLAGS_OFF_BYTES ((size_t)4 * SBUF_ELEMS * 2)   // 512 KiB
#define WS_BYTES (FLAGS_OFF_BYTES + 256 * 4)

// LDS: 128 KiB weights | 2 KiB h-stage | 16 KiB cross-wave partial reduce
#define HSTG_OFF 131072
#define RED_OFF  (131072 + 2048)
#define LDS_BYTES (RED_OFF + 16384)

#define BARRIER_DEADLINE_TICKS 4000000ull   // 40 ms @100MHz; sticky bail

__device__ __forceinline__ float sig_(float v) { return 1.0f / (1.0f + __expf(-v)); }

#define GLOADX4(dst, p) \
  asm volatile("global_load_dwordx4 %0, %1, off sc0 sc1" : "=v"(dst) : "v"(p))
#define GLOADX4_C(dst, p) \
  asm volatile("global_load_dwordx4 %0, %1, off" : "=v"(dst) : "v"(p))
#define GSTOREX4(p, v_) \
  asm volatile("global_store_dwordx4 %0, %1, off sc0 sc1" :: "v"(p), "v"(v_) : "memory")
#define VWAIT(N) do { \
  asm volatile("s_waitcnt vmcnt(" #N ")" ::: "memory"); \
  __builtin_amdgcn_sched_barrier(0); } while (0)

#define MFMA(a, b, c) __builtin_amdgcn_mfma_f32_16x16x32_f16(a, b, c, 0, 0, 0)

__device__ __forceinline__ f16x8 cvt8(float4 u, float4 v) {
  f16x8 r;
  r[0]=(f16)u.x; r[1]=(f16)u.y; r[2]=(f16)u.z; r[3]=(f16)u.w;
  r[4]=(f16)v.x; r[5]=(f16)v.y; r[6]=(f16)v.z; r[7]=(f16)v.w;
  return r;
}

// Grid barrier (proven r4-r8): all waves drain -> __syncthreads -> tid0
// publishes flags[b]=tgt (NC) -> wave 0 polls all 192 flags (dwordx4/lane,
// tid<48). Deadline-bail sticky.
__device__ __forceinline__ void grid_barrier(int* flags, int tgt, bool& bail) {
  asm volatile("s_waitcnt vmcnt(0)" ::: "memory");
  __syncthreads();
  if (threadIdx.x == 0) {
    int* fp = flags + blockIdx.x;
    asm volatile("global_store_dword %0, %1, off sc0 sc1" :: "v"(fp), "v"(tgt) : "memory");
  }
  if (threadIdx.x < 64 && !bail) {
    const int* pp = flags + (threadIdx.x << 2);
    const unsigned long long t0 = __builtin_amdgcn_s_memrealtime();
    for (;;) {
      int ok = 1;
      if (threadIdx.x < 48) {
        i32x4 f4;
        asm volatile("global_load_dwordx4 %0, %1, off sc0 sc1\n\ts_waitcnt vmcnt(0)"
                     : "=v"(f4) : "v"(pp) : "memory");
        ok = (f4[0] >= tgt) & (f4[1] >= tgt) & (f4[2] >= tgt) & (f4[3] >= tgt);
      }
      if (__all(ok)) break;
      if (__builtin_amdgcn_s_memrealtime() - t0 > BARRIER_DEADLINE_TICKS) { bail = true; break; }
      __builtin_amdgcn_s_sleep(1);
    }
  }
  __syncthreads();
}

__global__ __launch_bounds__(NTHR, 2) void lstm_fused(
    const float* __restrict__ x,
    const float* __restrict__ w_ih_0, const float* __restrict__ w_hh_0,
    const float* __restrict__ b_ih_0, const float* __restrict__ b_hh_0,
    const float* __restrict__ w_ih_1, const float* __restrict__ w_hh_1,
    const float* __restrict__ b_ih_1, const float* __restrict__ b_hh_1,
    const float* __restrict__ w_fc, const float* __restrict__ b_fc,
    float* __restrict__ out, void* __restrict__ ws)
{
  extern __shared__ char smem[];
  f16* wl = (f16*)smem;
  f16* hstg = (f16*)(smem + HSTG_OFF);
  float* red = (float*)(smem + RED_OFF);
  f16* ws16 = (f16*)ws;
  int* flags = (int*)((char*)ws + FLAGS_OFF_BYTES);

  const int b = blockIdx.x;
  const int tid = threadIdx.x;
  const int wave = tid >> 6, lane = tid & 63;
  const int quad = wave & 3, kh = wave >> 2;       // batch quadrant, K-half
  const int col = lane & 15, krow = lane >> 4;
  const bool isL1 = (b >= NL0B);
  bool bail = false;

  // ---- zero the S rings (512 KiB) via NC stores (drained at first barrier) ----
  {
    const int gt = b * NTHR + tid;
    if (gt < 32768) {
      i32x4 z = (i32x4){0, 0, 0, 0};
      char* p = (char*)ws + (size_t)gt * 16;
      GSTOREX4(p, z);
    }
  }

  if (!isL1) {
    // ============ LAYER 0: 64 blocks x 16 h-cols, 8 waves K-split ============
    // waves kh=0: x k[0:128) + s0 k[0:512);  kh=1: x k[128:256) + s0 k[512:1024)
    const int hc0 = b * 16;
    {   // stage w_hh_0 slice (K=1024, 64 gate-cols) -> wl [(k>>3)][64][8]
      const int c2 = tid >> 3, kpart = tid & 7;
      const int n = c2 >> 4, cc = c2 & 15;
      const int grow = n * 1024 + hc0 + cc;
      const float* src = w_hh_0 + (size_t)grow * 1024;
      for (int k = kpart * 128; k < kpart * 128 + 128; k += 4) {
        float4 v = *(const float4*)(src + k);
        f16x4 hv; hv[0]=(f16)v.x; hv[1]=(f16)v.y; hv[2]=(f16)v.z; hv[3]=(f16)v.w;
        *(f16x4*)&wl[((size_t)(k >> 3) * 64 + c2) * 8 + (k & 7)] = hv;
      }
    }
    // x-weights in VGPRs: this wave's K-half only -> wx[n*4+kc2]
    f16x8 wx[16];
#pragma unroll
    for (int n = 0; n < 4; ++n)
#pragma unroll
      for (int kc2 = 0; kc2 < 4; ++kc2) {
        const int kc = kh * 4 + kc2;
        const float* p = w_ih_0 + (size_t)(n * 1024 + hc0 + col) * 256 + kc * 32 + krow * 8;
        wx[n * 4 + kc2] = cvt8(*(const float4*)p, *(const float4*)(p + 4));
      }
    const int gi = hc0 + col;
    const float bi  = b_ih_0[gi]        + b_hh_0[gi];
    const float bf_ = b_ih_0[1024 + gi] + b_hh_0[1024 + gi];
    const float bg  = b_ih_0[2048 + gi] + b_hh_0[2048 + gi];
    const float bo  = b_ih_0[3072 + gi] + b_hh_0[3072 + gi];
    float creg[4] = {0.f, 0.f, 0.f, 0.f};   // valid on kh=0 waves only

    // prologue: this wave's x-half partial for t=0
    f32x4 accX0 = (f32x4){0,0,0,0}, accX1 = (f32x4){0,0,0,0};
    f32x4 accX2 = (f32x4){0,0,0,0}, accX3 = (f32x4){0,0,0,0};
    {
      const float* xb0 = x + (size_t)(16 * quad + col) * TT * INF + krow * 8;
#pragma unroll
      for (int kc2 = 0; kc2 < 4; ++kc2) {
        const int kc = kh * 4 + kc2;
        f16x8 ax = cvt8(*(const float4*)(xb0 + kc * 32), *(const float4*)(xb0 + kc * 32 + 4));
        accX0 = MFMA(ax, wx[0 * 4 + kc2], accX0);
        accX1 = MFMA(ax, wx[1 * 4 + kc2], accX1);
        accX2 = MFMA(ax, wx[2 * 4 + kc2], accX2);
        accX3 = MFMA(ax, wx[3 * 4 + kc2], accX3);
      }
    }
    grid_barrier(flags, 1, bail);

    const f16* WbL0 = wl + krow * 512 + col * 8;
    const int cb = kh * 16;   // s0 chunk base for this wave (chunks of 32 k)
    for (int r = 0; r <= TT; ++r) {
      if (r < TT) {
        f32x4 acc0 = accX0, acc1 = accX1, acc2 = accX2, acc3 = accX3;
        const f16* s0in = ws16 + (size_t)((r + 1) & 1) * SBUF_ELEMS;
        f16*       s0out = ws16 + (size_t)(r & 1) * SBUF_ELEMS;
        const bool dox = (r + 1) < TT;
        const float* xb = x + (size_t)(16 * quad + col) * TT * INF
                            + (size_t)(dox ? r + 1 : r) * INF + krow * 8;
        accX0 = (f32x4){0,0,0,0}; accX1 = (f32x4){0,0,0,0};
        accX2 = (f32x4){0,0,0,0}; accX3 = (f32x4){0,0,0,0};
        // ---- x phase (t=r+1, this K-half -> accX), cached loads ----
        {
          i32x4 xv[8];
#pragma unroll
          for (int i = 0; i < 8; ++i) {
            const float* p_ = xb + (kh * 4 + (i >> 1)) * 32 + (i & 1) * 4;
            GLOADX4_C(xv[i], p_);
          }
          VWAIT(0);
#pragma unroll
          for (int q = 0; q < 4; ++q) {
            f16x8 ax_ = cvt8(__builtin_bit_cast(float4, xv[2 * q]),
                             __builtin_bit_cast(float4, xv[2 * q + 1]));
            accX0 = MFMA(ax_, wx[0 * 4 + q], accX0);
            accX1 = MFMA(ax_, wx[1 * 4 + q], accX1);
            accX2 = MFMA(ax_, wx[2 * 4 + q], accX2);
            accX3 = MFMA(ax_, wx[3 * 4 + q], accX3);
          }
        }
        // ---- s0 half: 16 chunks, ring 8 ----
        {
          i32x4 av[8];
          const f16* Ab = s0in + (size_t)(16 * quad + col) * 1024 + krow * 8;
#pragma unroll
          for (int i = 0; i < 8; ++i) { const f16* p = Ab + (cb + i) * 32; GLOADX4(av[i], p); }
#define L0CONS4(SLOT0, C0) do { _Pragma("unroll") for (int q_ = 0; q_ < 4; ++q_) { \
    f16x8 a_ = __builtin_bit_cast(f16x8, av[(SLOT0) + q_]); \
    const f16* wp_ = WbL0 + (size_t)(cb + (C0) + q_) * 2048; \
    f16x8 w0_ = *(const f16x8*)(wp_); \
    f16x8 w1_ = *(const f16x8*)(wp_ + 128); \
    f16x8 w2_ = *(const f16x8*)(wp_ + 256); \
    f16x8 w3_ = *(const f16x8*)(wp_ + 384); \
    acc0 = MFMA(a_, w0_, acc0); acc1 = MFMA(a_, w1_, acc1); \
    acc2 = MFMA(a_, w2_, acc2); acc3 = MFMA(a_, w3_, acc3); } } while (0)
#define L0ISS4(SLOT0, C0) do { _Pragma("unroll") for (int q_ = 0; q_ < 4; ++q_) { \
    const f16* p_ = Ab + (size_t)(cb + (C0) + q_) * 32; \
    GLOADX4(av[(SLOT0) + q_], p_); } } while (0)
          VWAIT(4); L0CONS4(0, 0);  L0ISS4(0, 8);
          VWAIT(4); L0CONS4(4, 4);  L0ISS4(4, 12);
          VWAIT(4); L0CONS4(0, 8);
          VWAIT(0); L0CONS4(4, 12);
#undef L0CONS4
#undef L0ISS4
        }
        // ---- cross-wave partial combine via LDS ----
        if (kh == 1) {
          float* rp = red + (size_t)quad * 1024 + (size_t)lane * 16;
          *(f32x4*)(rp + 0)  = acc0;
          *(f32x4*)(rp + 4)  = acc1;
          *(f32x4*)(rp + 8)  = acc2;
          *(f32x4*)(rp + 12) = acc3;
        }
        __syncthreads();
        if (kh == 0) {
          const float* rp = red + (size_t)quad * 1024 + (size_t)lane * 16;
          acc0 += *(const f32x4*)(rp + 0);
          acc1 += *(const f32x4*)(rp + 4);
          acc2 += *(const f32x4*)(rp + 8);
          acc3 += *(const f32x4*)(rp + 12);
#pragma unroll
          for (int j = 0; j < 4; ++j) {
            float iv = acc0[j] + bi, fv = acc1[j] + bf_;
            float gv = acc2[j] + bg, ov = acc3[j] + bo;
            float cn = sig_(fv) * creg[j] + sig_(iv) * tanhf(gv);
            float hn = sig_(ov) * tanhf(cn);
            creg[j] = cn;
            hstg[(16 * quad + krow * 4 + j) * 16 + col] = (f16)hn;
          }
        }
        __syncthreads();
        if (tid < 64) {
          i32x4 v0 = *(const i32x4*)&hstg[tid * 16];
          i32x4 v1 = *(const i32x4*)&hstg[tid * 16 + 8];
          f16* p = s0out + (size_t)tid * 1024 + hc0;
          GSTOREX4(p, v0);
          f16* p2 = p + 8;
          GSTOREX4(p2, v1);
        }
      }
      grid_barrier(flags, r + 2, bail);
    }
  } else {
    // ============ LAYER 1: 128 blocks x 8 h-cols, 8 waves K-split ============
    // waves kh=0: A=s0[t-1], W=W_ih_1 (k 0..1023); kh=1: A=s1[t-2], W=W_hh_1
    const int bb = b - NL0B;
    const int hc0 = bb * 8;
    {   // stage K=2048 x 32 gate-cols -> wl [(k>>3)][32][8]
      const int c = tid >> 4, kpart = tid & 15;
      const int grp = c >> 3, sub = c & 7;
      const int grow = grp * 1024 + hc0 + sub;
      const float* srcA = w_ih_1 + (size_t)grow * 1024;
      const float* srcB = w_hh_1 + (size_t)grow * 1024;
      for (int k = kpart * 128; k < kpart * 128 + 128; k += 4) {
        const float* s = (k < 1024) ? (srcA + k) : (srcB + (k - 1024));
        float4 v = *(const float4*)s;
        f16x4 hv; hv[0]=(f16)v.x; hv[1]=(f16)v.y; hv[2]=(f16)v.z; hv[3]=(f16)v.w;
        *(f16x4*)&wl[((size_t)(k >> 3) * 32 + c) * 8 + (k & 7)] = hv;
      }
    }
    const int gi = hc0 + (col & 7);
    const float bi  = b_ih_1[gi]        + b_hh_1[gi];
    const float bf_ = b_ih_1[1024 + gi] + b_hh_1[1024 + gi];
    const float bg  = b_ih_1[2048 + gi] + b_hh_1[2048 + gi];
    const float bo  = b_ih_1[3072 + gi] + b_hh_1[3072 + gi];
    float creg[4] = {0.f, 0.f, 0.f, 0.f};   // kh=0 waves only

    grid_barrier(flags, 1, bail);

    const f16* Wb = wl + krow * 256 + col * 8;
    const int wcb = kh * 32;   // weight chunk base (32-k chunks)
    for (int r = 0; r <= TT; ++r) {
      if (r >= 1) {
        const f16* s0in = ws16 + (size_t)((r + 1) & 1) * SBUF_ELEMS;
        const f16* s1in = ws16 + S1_BASE + (size_t)(r & 1) * SBUF_ELEMS;
        f16*       s1out = ws16 + S1_BASE + (size_t)((r + 1) & 1) * SBUF_ELEMS;
        const f16* Asrc = (kh == 0) ? s0in : s1in;
        const f16* Ab = Asrc + (size_t)(16 * quad + col) * 1024 + krow * 8;
        f32x4 acc0 = (f32x4){0,0,0,0}, acc1 = (f32x4){0,0,0,0};
        // 32 chunks of this K-half, ring 16
        i32x4 av[16];
#pragma unroll
        for (int i = 0; i < 16; ++i) { const f16* p = Ab + i * 32; GLOADX4(av[i], p); }
#define L1CONS4(SLOT0, C0) do { _Pragma("unroll") for (int q_ = 0; q_ < 4; ++q_) { \
    f16x8 a_ = __builtin_bit_cast(f16x8, av[(SLOT0) + q_]); \
    const f16* wp_ = Wb + (size_t)(wcb + (C0) + q_) * 1024; \
    f16x8 w0_ = *(const f16x8*)(wp_); \
    f16x8 w1_ = *(const f16x8*)(wp_ + 128); \
    acc0 = MFMA(a_, w0_, acc0); acc1 = MFMA(a_, w1_, acc1); } } while (0)
#define L1ISS4(SLOT0, C0) do { _Pragma("unroll") for (int q_ = 0; q_ < 4; ++q_) { \
    const f16* p_ = Ab + (size_t)((C0) + q_) * 32; \
    GLOADX4(av[(SLOT0) + q_], p_); } } while (0)
        VWAIT(12); L1CONS4(0, 0);   L1ISS4(0, 16);
        VWAIT(12); L1CONS4(4, 4);   L1ISS4(4, 20);
        VWAIT(12); L1CONS4(8, 8);   L1ISS4(8, 24);
        VWAIT(12); L1CONS4(12, 12); L1ISS4(12, 28);
        VWAIT(12); L1CONS4(0, 16);
        VWAIT(8);  L1CONS4(4, 20);
        VWAIT(4);  L1CONS4(8, 24);
        VWAIT(0);  L1CONS4(12, 28);
#undef L1CONS4
#undef L1ISS4
        if (kh == 1) {
          float* rp = red + (size_t)quad * 1024 + (size_t)lane * 16;
          *(f32x4*)(rp + 0) = acc0;
          *(f32x4*)(rp + 4) = acc1;
        }
        __syncthreads();
        if (kh == 0) {
          const float* rp = red + (size_t)quad * 1024 + (size_t)lane * 16;
          acc0 += *(const f32x4*)(rp + 0);
          acc1 += *(const f32x4*)(rp + 4);
          f16 hv4[4];
#pragma unroll
          for (int j = 0; j < 4; ++j) {
            float iv = acc0[j], gv = acc1[j];
            float fv = __shfl_xor(iv, 8, 64);
            float ov = __shfl_xor(gv, 8, 64);
            iv += bi; fv += bf_; gv += bg; ov += bo;
            float cn = sig_(fv) * creg[j] + sig_(iv) * tanhf(gv);
            float hn = sig_(ov) * tanhf(cn);
            creg[j] = cn;
            hv4[j] = (f16)hn;
          }
          if (col < 8) {
#pragma unroll
            for (int j = 0; j < 4; ++j)
              hstg[(16 * quad + krow * 4 + j) * 8 + col] = hv4[j];
          }
        }
        __syncthreads();
        if (tid < 64) {
          i32x4 v0 = *(const i32x4*)&hstg[tid * 8];
          f16* p = s1out + (size_t)tid * 1024 + hc0;
          GSTOREX4(p, v0);
        }
      }
      grid_barrier(flags, r + 2, bail);
    }
  }

  // ---- FC on last timestep: cols c = b, b+192 ----
  {
    float* redf = (float*)smem;   // weights dead
    const f16* Afc = ws16 + S1_BASE + (size_t)1 * SBUF_ELEMS;   // s1[511] parity 1
    const int row = tid & 63, kq = tid >> 6;   // kq 0..7, 128-elem chunks
    for (int c = b; c < OUTF; c += NBLK) {
      const f16* ph = Afc + (size_t)row * 1024 + kq * 128;
      const float* pw = w_fc + (size_t)c * 1024 + kq * 128;
      float acc = 0.f;
#pragma unroll 4
      for (int k = 0; k < 128; ++k)
        acc = fmaf((float)ph[k], pw[k], acc);
      __syncthreads();
      redf[tid] = acc;
      __syncthreads();
      if (tid < 64) {
        float s = b_fc[c];
#pragma unroll
        for (int q = 0; q < 8; ++q) s += redf[tid + 64 * q];
        out[(size_t)tid * OUTF + c] = s;
      }
    }
  }
}

extern "C" void kernel_launch(void* const* d_in, const int* in_sizes, int n_in,
                              void* d_out, int out_size, void* d_ws, size_t ws_size,
                              hipStream_t stream) {
  const float* x      = (const float*)d_in[0];
  const float* w_ih_0 = (const float*)d_in[1];
  const float* w_hh_0 = (const float*)d_in[2];
  const float* b_ih_0 = (const float*)d_in[3];
  const float* b_hh_0 = (const float*)d_in[4];
  const float* w_ih_1 = (const float*)d_in[5];
  const float* w_hh_1 = (const float*)d_in[6];
  const float* b_ih_1 = (const float*)d_in[7];
  const float* b_hh_1 = (const float*)d_in[8];
  const float* w_fc   = (const float*)d_in[9];
  const float* b_fc   = (const float*)d_in[10];
  float* out = (float*)d_out;
  void* ws = d_ws;

  if (ws_size < WS_BYTES) return;   // clean failure signature, no VM fault

  hipMemsetAsync((char*)d_ws + FLAGS_OFF_BYTES, 0, 256 * 4, stream);
  hipFuncSetAttribute((const void*)lstm_fused,
                      hipFuncAttributeMaxDynamicSharedMemorySize, LDS_BYTES);

  void* args[] = {
    (void*)&x, (void*)&w_ih_0, (void*)&w_hh_0, (void*)&b_ih_0, (void*)&b_hh_0,
    (void*)&w_ih_1, (void*)&w_hh_1, (void*)&b_ih_1, (void*)&b_hh_1,
    (void*)&w_fc, (void*)&b_fc, (void*)&out, (void*)&ws
  };
  hipError_t err = hipLaunchCooperativeKernel((void*)lstm_fused, dim3(NBLK), dim3(NTHR),
                                              args, LDS_BYTES, stream);
  if (err != hipSuccess) {
    (void)hipGetLastError();
    lstm_fused<<<dim3(NBLK), dim3(NTHR), LDS_BYTES, stream>>>(
        x, w_ih_0, w_hh_0, b_ih_0, b_hh_0, w_ih_1, w_hh_1, b_ih_1, b_hh_1,
        w_fc, b_fc, out, ws);
  }
}